// Round 7
// baseline (1094.022 us; speedup 1.0000x reference)
//
#include <hip/hip_runtime.h>
#include <hip/hip_bf16.h>

// Problem constants:
#define BATCH 8
#define NQ    75
#define WAY   5
#define PN    121
#define DIM   640
#define SSZ   605        // shot * patch_num
#define TOPK  3

#define KCH 10           // DIM / 64
#define NCH 5            // 640 / 128

// Workspace: bf16, MFMA-tile-packed, XOR-swizzled (chunk_phys = chunk_log ^ (row&7)).
//   Q: [bq=600][kc=10] tiles of [row=128][chunk=8]x16B  (6000 tiles)
//   S: [bw=40][nc=5][kc=10] tiles                        (2000 tiles)
#define NQTILES 6000
#define NSTILES 2000
#define WS_NEED   ((size_t)(NQTILES + NSTILES) * 16384)   // 131,072,000 B

typedef __attribute__((ext_vector_type(8))) short   short8;
typedef __attribute__((ext_vector_type(8))) __bf16  bf16x8;
typedef __attribute__((ext_vector_type(4))) float   f32x4;

__device__ inline unsigned short f2bf(float f) {
  unsigned u = __builtin_bit_cast(unsigned, f);
  return (unsigned short)((u + 0x7fffu + ((u >> 16) & 1u)) >> 16);
}
__device__ inline unsigned pk2(float lo, float hi) {
  return (unsigned)f2bf(lo) | ((unsigned)f2bf(hi) << 16);
}

// branchless insert into sorted-descending triple: 1 max + 2 med3
__device__ inline void ins3(float &a, float &b, float &c, float v) {
  float na  = fmaxf(a, v);
  float nb  = __builtin_amdgcn_fmed3f(v, a, b);
  float nc2 = __builtin_amdgcn_fmed3f(v, b, c);
  a = na; b = nb; c = nc2;
}

// async 16B global->LDS (DMA; LDS dest = wave-uniform base + lane*16)
__device__ inline void async_copy16(const void* g, void* l) {
  __builtin_amdgcn_global_load_lds(
      (const __attribute__((address_space(1))) unsigned int*)g,
      (__attribute__((address_space(3))) unsigned int*)l, 16, 0, 0);
}

// ---------------- pack unit: one 32-row quarter of one tile frame ------------
// Math HW-verified (rounds 3-6 all passed with this pack path).
__device__ __forceinline__ void pack_unit(int unit_b, int j,
                                          const float* __restrict__ qf,
                                          const float* __restrict__ sf,
                                          uint4* __restrict__ wq,
                                          uint4* __restrict__ wsp) {
  const float* src;      // frame base (row 0 of the 128-row tile frame)
  uint4* dstbase;        // first kc tile of this frame
  int nrows, rowbase;
  if (j < 300) {
    const int q = j >> 2;
    rowbase = (j & 3) << 5;
    const int slab = unit_b * NQ + q;
    src = qf + (size_t)slab * PN * DIM;
    dstbase = wq + (size_t)slab * KCH * 1024;
    nrows = PN;
  } else {
    const int l = j - 300;
    rowbase = (l & 3) << 5;
    const int fi = l >> 2;          // 0..24 = w*5 + nc
    const int nc = fi % NCH;
    const int w  = fi / NCH;
    const int bw = unit_b * WAY + w;
    const int uv = bw * NCH + nc;
    src = sf + ((size_t)bw * SSZ + nc * 128) * DIM;
    dstbase = wsp + (size_t)uv * KCH * 1024;
    nrows = SSZ - nc * 128; if (nrows > 128) nrows = 128;
  }
  // 32 rows x 80 segments (8 floats in, 16B out each) = 2560 segs, 10 iters.
  #pragma unroll 2
  for (int i = 0; i < 10; ++i) {
    const int L    = i * 256 + threadIdx.x;   // 0..2559
    const int rowl = L / 80;
    const int s    = L - rowl * 80;           // 0..79: global 8-float segment
    const int row  = rowbase + rowl;          // tile-local row 0..127
    const int kc   = s >> 3;
    const int c    = s & 7;                   // logical chunk within kc window
    const int p    = c ^ (row & 7);           // physical chunk slot (swizzle)
    uint4 o = make_uint4(0u, 0u, 0u, 0u);
    if (row < nrows) {
      const float* g = src + (size_t)row * DIM + s * 8;
      float4 v0 = reinterpret_cast<const float4*>(g)[0];
      float4 v1 = reinterpret_cast<const float4*>(g)[1];
      o.x = pk2(v0.x, v0.y); o.y = pk2(v0.z, v0.w);
      o.z = pk2(v1.x, v1.y); o.w = pk2(v1.z, v1.w);
    }
    dstbase[(size_t)kc * 1024 + row * 8 + p] = o;
  }
}

// ---------------- pack kernel (standalone; ~60-90us, near its 60us roofline)
__global__ __launch_bounds__(256) void cvt_pack(const float* __restrict__ qf,
                                                const float* __restrict__ sf,
                                                uint4* __restrict__ wq,
                                                uint4* __restrict__ wsp) {
  const int blk = blockIdx.x;
  int b, j0;
  if (blk < 1200) { const int slab = blk >> 1; b = slab / NQ;
    j0 = (slab - b * NQ) * 4 + (blk & 1) * 2; }
  else { const int u = blk - 1200; const int uv = u >> 1;   // bw*5+nc
    const int bw = uv / NCH; b = bw / WAY;
    const int fi = (bw - b * WAY) * NCH + (uv % NCH);
    j0 = 300 + fi * 4 + (u & 1) * 2; }
  pack_unit(b, j0, qf, sf, wq, wsp);
  pack_unit(b, j0 + 1, qf, sf, wq, wsp);
}

// ---------------- main kernel v4: 384x128 tile, counted-vmcnt dbuf pipeline --
// Models locked in by R0/R1/R5/R6:
//  * staging BW: 2-barrier drain needs >=2 blocks/CU for ~14 TB/s (R0);
//    counted-vmcnt schedule sustains ~11.7 TB/s regardless of blocks (R1).
//  * regs (UNIFIED VGPR+AGPR, cap = 512/(waves/SIMD)): the 64x64-quadrant
//    wave needs ~164 -> 3 waves/SIMD max (cap 170). R6's (512,4) cap=128
//    spilled 550MB. So multi-block + big tile is impossible -> take the
//    counted-vmcnt route at 1 block with maximum FLOP/staged-byte.
//  * FETCH ~= workspace (L3-resident); HBM irrelevant. Staging BW is binding.
// This version: BM=384 (3 Q frames; 75=25x3 -> zero M pad), BN=128:
// 98 FLOP/B, staged total 3.2GB -> @11.7 TB/s ~= 274us vs R0's 345.
// 12 waves (768 thr) = 3 waves/SIMD, each the PROVEN 64x64 quadrant.
// R1's verified pipeline: LDS dbuf, depth-2 prefetch, per-wave counted
// vmcnt (A-waves 6 loads -> vmcnt(6), B-waves 4 -> vmcnt(4)), raw s_barrier.
// Loads stay in flight across barriers; only the last step drains.
__global__ __launch_bounds__(768, 3) void lpc_main(
    const char* __restrict__ wq,    // packed Q tiles
    const char* __restrict__ wsp,   // packed S tiles
    float* __restrict__ out)        // [B, NQ, WAY]
{
  __shared__ char As[2][49152];     // 384 rows x 64 K bf16 (three 128-row frames)
  __shared__ char Bs[2][16384];     // 128 S-cols x 64 K bf16
  __shared__ float red[12];

  const int sbid = blockIdx.x;      // grid 1000 = 8 batches x 25 qt x 5 w
  const int b    = sbid & 7;        // 1000 % 8 == 0: XCD k owns batch k
  const int bid2 = sbid >> 3;       // 0..124
  const int w    = bid2 % WAY;
  const int qt   = bid2 / WAY;      // 0..24 (consecutive 5 blocks share qt)
  const int q0   = qt * 3;          // q0, q0+1, q0+2 all valid (75 = 25*3)

  const char* Qt0 = wq + (size_t)(b * NQ + q0) * KCH * 16384;
  const char* St  = wsp + (size_t)(b * WAY + w) * NCH * KCH * 16384;

  const int tid  = threadIdx.x;
  const int lane = tid & 63;
  const int wv   = tid >> 6;            // 0..11
  const int l15  = lane & 15;
  const int quad = lane >> 4;
  const int mrow0 = (wv >> 1) * 64;     // 0,64,...,320
  const int ncol0 = (wv & 1) * 64;      // 0,64

  // swizzled chunk byte offsets (XOR distributes over the <<4); row&7 == l15&7
  // since mrow0 is a multiple of 64.
  const int sw16 = (l15 & 7) * 16;
  const int cp0  = (quad * 16) ^ sw16;        // kk = 0
  const int cp1  = ((4 + quad) * 16) ^ sw16;  // kk = 1

  // staging: 64 x 1KB chunks/step. A (3 frames) = chunks 0..47: waves 0..7 own
  // 6 each; B = chunks 0..15 of Bs: waves 8..11 own 4 each. Frame f of chunk
  // ch = ch>>4 (consecutive q slabs: base = Qt0 + f*KCH*16384).
  auto stage = [&](int buf, int tt, int kcc) {
    if (wv < 8) {
      #pragma unroll
      for (int i = 0; i < 6; ++i) {
        const int ch = wv * 6 + i;
        const char* src = Qt0 + (size_t)(ch >> 4) * (KCH * 16384)
                        + (size_t)kcc * 16384 + (ch & 15) * 1024;
        async_copy16(src + lane * 16, &As[buf][0] + ch * 1024);
      }
    } else {
      #pragma unroll
      for (int i = 0; i < 4; ++i) {
        const int ch = (wv - 8) * 4 + i;
        const char* src = St + (size_t)tt * 16384 + ch * 1024;
        async_copy16(src + lane * 16, &Bs[buf][0] + ch * 1024);
      }
    }
  };

  // per-lane running top-3 for 16 owned rows: row = mrow0 + mt*16 + quad*4 + r
  float t3a[4][4], t3b[4][4], t3c[4][4];
  #pragma unroll
  for (int mt = 0; mt < 4; ++mt)
    #pragma unroll
    for (int r = 0; r < 4; ++r) {
      t3a[mt][r] = -3.0e38f; t3b[mt][r] = -3.0e38f; t3c[mt][r] = -3.0e38f;
    }

  // prologue: depth-2 — step 0 -> buf0, step 1 -> buf1 (in flight)
  stage(0, 0, 0);
  stage(1, 1, 1);

  f32x4 acc[4][4];
  int kc = 0, nc = 0, kc2 = 2;

  // 50 flattened K-steps; S tile index == t (S slab linear in (nc,kc)).
  #pragma unroll 1
  for (int t = 0; t < NCH * KCH; ++t) {
    const int cur = t & 1;

    if (kc == 0) {   // register-only; overlaps in-flight DMA
      #pragma unroll
      for (int mt = 0; mt < 4; ++mt)
        #pragma unroll
        for (int nt = 0; nt < 4; ++nt)
          acc[mt][nt] = (f32x4){0.f, 0.f, 0.f, 0.f};
    }

    // Counted per-wave wait: outstanding = stage(t)+stage(t+1); retire
    // stage(t) only (in-order), stage(t+1) stays in flight across the barrier.
    if (t < 49) {
      if (wv < 8) asm volatile("s_waitcnt vmcnt(6)" ::: "memory");
      else        asm volatile("s_waitcnt vmcnt(4)" ::: "memory");
    } else {
      asm volatile("s_waitcnt vmcnt(0)" ::: "memory");
    }
    asm volatile("s_barrier" ::: "memory");   // all waves' step-t data in LDS

    const char* qb = &As[cur][0] + (mrow0 + l15) * 128;
    const char* sb = &Bs[cur][0] + (ncol0 + l15) * 128;

    __builtin_amdgcn_s_setprio(1);
    #pragma unroll
    for (int kk = 0; kk < 2; ++kk) {
      const int cp = kk ? cp1 : cp0;
      short8 a[4], bf[4];
      #pragma unroll
      for (int mt = 0; mt < 4; ++mt)
        a[mt] = *reinterpret_cast<const short8*>(qb + mt * 2048 + cp);
      #pragma unroll
      for (int nt = 0; nt < 4; ++nt)
        bf[nt] = *reinterpret_cast<const short8*>(sb + nt * 2048 + cp);
      #pragma unroll
      for (int mt = 0; mt < 4; ++mt)
        #pragma unroll
        for (int nt = 0; nt < 4; ++nt)
          acc[mt][nt] = __builtin_amdgcn_mfma_f32_16x16x32_bf16(
              __builtin_bit_cast(bf16x8, a[mt]),
              __builtin_bit_cast(bf16x8, bf[nt]), acc[mt][nt], 0, 0, 0);
    }
    __builtin_amdgcn_s_setprio(0);

    if (kc == 9) {
      // fold this 128-col chunk into register top-3 (mask pad cols >= 605)
      #pragma unroll
      for (int nt = 0; nt < 4; ++nt) {
        const int col = nc * 128 + ncol0 + nt * 16 + l15;
        const bool valid = col < SSZ;
        #pragma unroll
        for (int mt = 0; mt < 4; ++mt)
          #pragma unroll
          for (int r = 0; r < 4; ++r) {
            float v = valid ? acc[mt][nt][r] : -3.0e38f;
            ins3(t3a[mt][r], t3b[mt][r], t3c[mt][r], v);
          }
      }
      kc = 0; ++nc;
    } else {
      ++kc;
    }

    // all waves done reading buf[cur] before its DMA overwrite is issued
    asm volatile("s_barrier" ::: "memory");

    if (t < 48) stage(cur, t + 2, kc2);   // (t+2)&1 == cur
    kc2 = (kc2 == 9) ? 0 : kc2 + 1;
  }

  // butterfly-merge top-3 across the 16 l15 lanes (same rows, different cols)
  #pragma unroll
  for (int m = 1; m < 16; m <<= 1) {
    #pragma unroll
    for (int mt = 0; mt < 4; ++mt)
      #pragma unroll
      for (int r = 0; r < 4; ++r) {
        float o0 = __shfl_xor(t3a[mt][r], m);
        float o1 = __shfl_xor(t3b[mt][r], m);
        float o2 = __shfl_xor(t3c[mt][r], m);
        ins3(t3a[mt][r], t3b[mt][r], t3c[mt][r], o0);
        ins3(t3a[mt][r], t3b[mt][r], t3c[mt][r], o1);
        ins3(t3a[mt][r], t3b[mt][r], t3c[mt][r], o2);
      }
  }

  // cross-N-wave merge via LDS scratch (reuse As; all DMA retired by the
  // t=49 vmcnt(0)): odd waves publish; even waves (same mrow0) merge and
  // republish. tb[384][3] = 4.6KB.
  float* tb = reinterpret_cast<float*>(&As[0][0]);
  __syncthreads();
  if ((wv & 1) == 1 && l15 == 0) {
    #pragma unroll
    for (int mt = 0; mt < 4; ++mt)
      #pragma unroll
      for (int r = 0; r < 4; ++r) {
        int row = mrow0 + mt * 16 + quad * 4 + r;
        tb[row * 3 + 0] = t3a[mt][r];
        tb[row * 3 + 1] = t3b[mt][r];
        tb[row * 3 + 2] = t3c[mt][r];
      }
  }
  __syncthreads();
  if ((wv & 1) == 0 && l15 == 0) {
    #pragma unroll
    for (int mt = 0; mt < 4; ++mt)
      #pragma unroll
      for (int r = 0; r < 4; ++r) {
        int row = mrow0 + mt * 16 + quad * 4 + r;
        ins3(t3a[mt][r], t3b[mt][r], t3c[mt][r], tb[row * 3 + 0]);
        ins3(t3a[mt][r], t3b[mt][r], t3c[mt][r], tb[row * 3 + 1]);
        ins3(t3a[mt][r], t3b[mt][r], t3c[mt][r], tb[row * 3 + 2]);
      }
  }
  __syncthreads();
  if ((wv & 1) == 0 && l15 == 0) {
    #pragma unroll
    for (int mt = 0; mt < 4; ++mt)
      #pragma unroll
      for (int r = 0; r < 4; ++r) {
        int row = mrow0 + mt * 16 + quad * 4 + r;
        tb[row * 3 + 0] = t3a[mt][r];
        tb[row * 3 + 1] = t3b[mt][r];
        tb[row * 3 + 2] = t3c[mt][r];
      }
  }
  __syncthreads();

  // mean over valid rows and k: frame h (rows h*128..h*128+120) -> q0+h.
  // thread third h = tid>>8 handles frame h (waves 4h..4h+3 == wv>>2 == h).
  const int third = tid >> 8;
  float s = 0.f;
  for (int j = tid & 255; j < PN * TOPK; j += 256) s += tb[third * 384 + j];
  #pragma unroll
  for (int off = 32; off > 0; off >>= 1) s += __shfl_down(s, off);
  if (lane == 0) red[wv] = s;
  __syncthreads();
  if ((tid & 255) == 0) {
    const int r0 = third * 4;
    out[(size_t)(b * NQ + q0 + third) * WAY + w] =
        (red[r0] + red[r0 + 1] + red[r0 + 2] + red[r0 + 3]) *
        (1.0f / (PN * TOPK));
  }
}

// ---------------- fallback (direct from fp32, only if ws too small) ---------
__global__ __launch_bounds__(256) void lpc_fallback(
    const float* __restrict__ qf, const float* __restrict__ sf,
    float* __restrict__ out)
{
  __shared__ short Qst[128][72];
  __shared__ short Sst[64][72];
  __shared__ float Cs[128][67];
  __shared__ float top3[128][TOPK];
  __shared__ float red[4];

  const int bid = blockIdx.x;
  const int w   = bid % WAY;
  const int qi  = (bid / WAY) % NQ;
  const int b   = bid / (WAY * NQ);
  const float* Qb = qf + ((size_t)(b * NQ + qi)) * PN * DIM;
  const float* Sb = sf + ((size_t)(b * WAY + w)) * SSZ * DIM;
  const int tid  = threadIdx.x;
  const int lane = tid & 63;
  const int wv   = tid >> 6;
  const int l15  = lane & 15;
  const int quad = lane >> 4;

  if (tid < 128) { top3[tid][0] = -3.0e38f; top3[tid][1] = -3.0e38f; top3[tid][2] = -3.0e38f; }
  f32x4 acc[2][4];
  for (int nc = 0; nc < 10; ++nc) {
    const int sbase = nc * 64;
    int vn = SSZ - sbase; if (vn > 64) vn = 64;
    #pragma unroll
    for (int mt = 0; mt < 2; ++mt)
      #pragma unroll
      for (int nt = 0; nt < 4; ++nt) acc[mt][nt] = (f32x4){0.f,0.f,0.f,0.f};
    for (int kc = 0; kc < KCH; ++kc) {
      const int kbase = kc * 64;
      __syncthreads();
      #pragma unroll
      for (int i = 0; i < 8; ++i) {
        int lin = i * 256 + tid; int row = lin >> 4; int c4 = lin & 15;
        float4 v = make_float4(0.f,0.f,0.f,0.f);
        if (row < PN) v = *reinterpret_cast<const float4*>(Qb + (size_t)row * DIM + kbase + c4 * 4);
        ushort4 h; h.x=f2bf(v.x); h.y=f2bf(v.y); h.z=f2bf(v.z); h.w=f2bf(v.w);
        *reinterpret_cast<ushort4*>(&Qst[row][c4*4]) = h;
      }
      #pragma unroll
      for (int i = 0; i < 4; ++i) {
        int lin = i * 256 + tid; int row = lin >> 4; int c4 = lin & 15;
        int srow = sbase + row;
        float4 v = make_float4(0.f,0.f,0.f,0.f);
        if (srow < SSZ) v = *reinterpret_cast<const float4*>(Sb + (size_t)srow * DIM + kbase + c4 * 4);
        ushort4 h; h.x=f2bf(v.x); h.y=f2bf(v.y); h.z=f2bf(v.z); h.w=f2bf(v.w);
        *reinterpret_cast<ushort4*>(&Sst[row][c4*4]) = h;
      }
      __syncthreads();
      #pragma unroll
      for (int kk = 0; kk < 2; ++kk) {
        bf16x8 a0 = __builtin_bit_cast(bf16x8, *reinterpret_cast<const short8*>(&Qst[wv*32+ 0+l15][kk*32+quad*8]));
        bf16x8 a1 = __builtin_bit_cast(bf16x8, *reinterpret_cast<const short8*>(&Qst[wv*32+16+l15][kk*32+quad*8]));
        #pragma unroll
        for (int nt = 0; nt < 4; ++nt) {
          bf16x8 bb = __builtin_bit_cast(bf16x8, *reinterpret_cast<const short8*>(&Sst[nt*16+l15][kk*32+quad*8]));
          acc[0][nt] = __builtin_amdgcn_mfma_f32_16x16x32_bf16(a0, bb, acc[0][nt], 0,0,0);
          acc[1][nt] = __builtin_amdgcn_mfma_f32_16x16x32_bf16(a1, bb, acc[1][nt], 0,0,0);
        }
      }
    }
    #pragma unroll
    for (int mt = 0; mt < 2; ++mt)
      #pragma unroll
      for (int nt = 0; nt < 4; ++nt)
        #pragma unroll
        for (int r = 0; r < 4; ++r)
          Cs[wv*32+mt*16+quad*4+r][nt*16+l15] = acc[mt][nt][r];
    __syncthreads();
    {
      int row = tid >> 1; int half = tid & 1;
      float a = -3.0e38f, b2 = -3.0e38f, c = -3.0e38f;
      int c0 = half * 32; int cend = c0 + 32; if (cend > vn) cend = vn;
      for (int cc = c0; cc < cend; ++cc) ins3(a, b2, c, Cs[row][cc]);
      float o0 = __shfl_xor(a,1), o1 = __shfl_xor(b2,1), o2 = __shfl_xor(c,1);
      ins3(a,b2,c,o0); ins3(a,b2,c,o1); ins3(a,b2,c,o2);
      if (half == 0) {
        float r0=top3[row][0], r1=top3[row][1], r2=top3[row][2];
        ins3(r0,r1,r2,a); ins3(r0,r1,r2,b2); ins3(r0,r1,r2,c);
        top3[row][0]=r0; top3[row][1]=r1; top3[row][2]=r2;
      }
    }
    __syncthreads();
  }
  float s = 0.f;
  for (int i = tid; i < PN * TOPK; i += 256) s += top3[i/TOPK][i%TOPK];
  #pragma unroll
  for (int off = 32; off > 0; off >>= 1) s += __shfl_down(s, off);
  if (lane == 0) red[wv] = s;
  __syncthreads();
  if (tid == 0) out[bid] = (red[0]+red[1]+red[2]+red[3]) * (1.0f/(PN*TOPK));
}

// ---------------- launch ----------------
extern "C" void kernel_launch(void* const* d_in, const int* in_sizes, int n_in,
                              void* d_out, int out_size, void* d_ws, size_t ws_size,
                              hipStream_t stream) {
  const float* qf = (const float*)d_in[0];
  const float* sf = (const float*)d_in[1];
  float* out = (float*)d_out;
  (void)in_sizes; (void)n_in; (void)out_size;

  if (ws_size >= WS_NEED && d_ws != nullptr) {
    uint4* wq  = (uint4*)d_ws;
    uint4* wsp = wq + (size_t)NQTILES * 1024;
    cvt_pack<<<1600, 256, 0, stream>>>(qf, sf, wq, wsp);
    lpc_main<<<1000, 768, 0, stream>>>((const char*)wq, (const char*)wsp, out);
  } else {
    lpc_fallback<<<BATCH * NQ * WAY, 256, 0, stream>>>(qf, sf, out);
  }
}

// Round 8
// 865.591 us; speedup vs baseline: 1.2639x; 1.2639x over previous
//
#include <hip/hip_runtime.h>
#include <hip/hip_bf16.h>

// Problem constants:
#define BATCH 8
#define NQ    75
#define WAY   5
#define PN    121
#define DIM   640
#define SSZ   605        // shot * patch_num
#define TOPK  3

#define KCH 10           // DIM / 64
#define NCH 5            // 640 / 128

// Workspace: bf16, MFMA-tile-packed, XOR-swizzled (chunk_phys = chunk_log ^ (row&7)).
//   Q: [bq=600][kc=10] tiles of [row=128][chunk=8]x16B  (6000 tiles)
//   S: [bw=40][nc=5][kc=10] tiles                        (2000 tiles)
#define NQTILES 6000
#define NSTILES 2000
#define WS_NEED   ((size_t)(NQTILES + NSTILES) * 16384)   // 131,072,000 B

typedef __attribute__((ext_vector_type(8))) short   short8;
typedef __attribute__((ext_vector_type(8))) __bf16  bf16x8;
typedef __attribute__((ext_vector_type(4))) float   f32x4;

__device__ inline unsigned short f2bf(float f) {
  unsigned u = __builtin_bit_cast(unsigned, f);
  return (unsigned short)((u + 0x7fffu + ((u >> 16) & 1u)) >> 16);
}
__device__ inline unsigned pk2(float lo, float hi) {
  return (unsigned)f2bf(lo) | ((unsigned)f2bf(hi) << 16);
}

// branchless insert into sorted-descending triple: 1 max + 2 med3
__device__ inline void ins3(float &a, float &b, float &c, float v) {
  float na  = fmaxf(a, v);
  float nb  = __builtin_amdgcn_fmed3f(v, a, b);
  float nc2 = __builtin_amdgcn_fmed3f(v, b, c);
  a = na; b = nb; c = nc2;
}

// ---------------- pack unit: one 32-row quarter of one tile frame ------------
// Math HW-verified (rounds 3-7 all passed with this pack path).
__device__ __forceinline__ void pack_unit(int unit_b, int j,
                                          const float* __restrict__ qf,
                                          const float* __restrict__ sf,
                                          uint4* __restrict__ wq,
                                          uint4* __restrict__ wsp) {
  const float* src;      // frame base (row 0 of the 128-row tile frame)
  uint4* dstbase;        // first kc tile of this frame
  int nrows, rowbase;
  if (j < 300) {
    const int q = j >> 2;
    rowbase = (j & 3) << 5;
    const int slab = unit_b * NQ + q;
    src = qf + (size_t)slab * PN * DIM;
    dstbase = wq + (size_t)slab * KCH * 1024;
    nrows = PN;
  } else {
    const int l = j - 300;
    rowbase = (l & 3) << 5;
    const int fi = l >> 2;          // 0..24 = w*5 + nc
    const int nc = fi % NCH;
    const int w  = fi / NCH;
    const int bw = unit_b * WAY + w;
    const int uv = bw * NCH + nc;
    src = sf + ((size_t)bw * SSZ + nc * 128) * DIM;
    dstbase = wsp + (size_t)uv * KCH * 1024;
    nrows = SSZ - nc * 128; if (nrows > 128) nrows = 128;
  }
  // 32 rows x 80 segments (8 floats in, 16B out each) = 2560 segs, 10 iters.
  #pragma unroll 2
  for (int i = 0; i < 10; ++i) {
    const int L    = i * 256 + threadIdx.x;   // 0..2559
    const int rowl = L / 80;
    const int s    = L - rowl * 80;           // 0..79: global 8-float segment
    const int row  = rowbase + rowl;          // tile-local row 0..127
    const int kc   = s >> 3;
    const int c    = s & 7;                   // logical chunk within kc window
    const int p    = c ^ (row & 7);           // physical chunk slot (swizzle)
    uint4 o = make_uint4(0u, 0u, 0u, 0u);
    if (row < nrows) {
      const float* g = src + (size_t)row * DIM + s * 8;
      float4 v0 = reinterpret_cast<const float4*>(g)[0];
      float4 v1 = reinterpret_cast<const float4*>(g)[1];
      o.x = pk2(v0.x, v0.y); o.y = pk2(v0.z, v0.w);
      o.z = pk2(v1.x, v1.y); o.w = pk2(v1.z, v1.w);
    }
    dstbase[(size_t)kc * 1024 + row * 8 + p] = o;
  }
}

// ---------------- pack kernel (standalone; ~60-90us, near its 60us roofline)
__global__ __launch_bounds__(256) void cvt_pack(const float* __restrict__ qf,
                                                const float* __restrict__ sf,
                                                uint4* __restrict__ wq,
                                                uint4* __restrict__ wsp) {
  const int blk = blockIdx.x;
  int b, j0;
  if (blk < 1200) { const int slab = blk >> 1; b = slab / NQ;
    j0 = (slab - b * NQ) * 4 + (blk & 1) * 2; }
  else { const int u = blk - 1200; const int uv = u >> 1;   // bw*5+nc
    const int bw = uv / NCH; b = bw / WAY;
    const int fi = (bw - b * WAY) * NCH + (uv % NCH);
    j0 = 300 + fi * 4 + (u & 1) * 2; }
  pack_unit(b, j0, qf, sf, wq, wsp);
  pack_unit(b, j0 + 1, qf, sf, wq, wsp);
}

// ---------------- main kernel v5: NO LDS staging, register-direct fragments --
// Evidence through R7: per-CU gload_lds staging BW scales with resident
// BLOCKS (3 blk: 13.9 TB/s, 2: 11.7, 1: 8.0/3.9) because any barrier-synced
// schedule serializes the one block's DMA queue; every intra-block pipeline
// (R1/R5/R6/R7) lost to R0's inter-block TLP. This version removes the
// mechanism entirely: fragment byte offsets within a packed tile are
// PER-LANE CONSTANTS, so each wave global_loads its A/B fragments directly
// to registers. No LDS in the K-loop, no __syncthreads, no vmcnt(0) drain
// anywhere — each wave is pure load->MFMA dataflow (the AITER interleave,
// compiler-scheduled), 12 independent waves/CU hide L2 latency.
// Cost: A,B each read by 2 waves -> 9.6 GB from L1/L2 (L3-resident ws);
// per-XCD 1.2 GB / 4.3 TB/s ~= 280us bound vs MFMA floor 138us.
// Geometry/fold/epilogue = R0 verbatim (proven). Regs ~100 VGPR + 64 AGPR
// <= 170 cap at (256,3) -> 12 waves/CU, no spill (WRITE_SIZE is the check).
__global__ __launch_bounds__(256, 3) void lpc_main(
    const char* __restrict__ wq,    // packed Q tiles
    const char* __restrict__ wsp,   // packed S tiles
    float* __restrict__ out)        // [B, NQ, WAY]
{
  __shared__ float tb[128 * TOPK];  // epilogue scratch only (1.5 KB)
  __shared__ float red[4];

  // XCD swizzle: XCD k owns batch k (3000 = 8*375).
  const int sbid = blockIdx.x;
  const int bid  = (sbid & 7) * (NQ * WAY) + (sbid >> 3);

  const int w   = bid % WAY;
  const int bq  = bid / WAY;            // b*NQ + q
  const int b   = bid / (WAY * NQ);

  const char* Qtiles = wq  + (size_t)bq * KCH * 16384;
  const char* Stiles = wsp + (size_t)(b * WAY + w) * NCH * KCH * 16384;

  const int tid  = threadIdx.x;
  const int lane = tid & 63;
  const int wv   = tid >> 6;
  const int l15  = lane & 15;
  const int quad = lane >> 4;
  const int mrow0 = (wv >> 1) * 64;     // quadrant row base
  const int ncol0 = (wv & 1) * 64;      // quadrant col base

  // per-lane fragment byte offsets within a 16KB tile (XOR swizzle folded in)
  const int sw16 = (l15 & 7) * 16;
  const int cp0  = (quad * 16) ^ sw16;        // kk = 0
  const int cp1  = ((4 + quad) * 16) ^ sw16;  // kk = 1
  const unsigned aoff0 = (unsigned)((mrow0 + l15) * 128 + cp0);
  const unsigned aoff1 = (unsigned)((mrow0 + l15) * 128 + cp1);
  const unsigned boff0 = (unsigned)((ncol0 + l15) * 128 + cp0);
  const unsigned boff1 = (unsigned)((ncol0 + l15) * 128 + cp1);

  // per-lane running top-3 for 16 owned rows: row = mrow0 + mt*16 + quad*4 + r
  float t3a[4][4], t3b[4][4], t3c[4][4];
  #pragma unroll
  for (int mt = 0; mt < 4; ++mt)
    #pragma unroll
    for (int r = 0; r < 4; ++r) {
      t3a[mt][r] = -3.0e38f; t3b[mt][r] = -3.0e38f; t3c[mt][r] = -3.0e38f;
    }

  for (int nc = 0; nc < NCH; ++nc) {
    f32x4 acc[4][4];
    #pragma unroll
    for (int mt = 0; mt < 4; ++mt)
      #pragma unroll
      for (int nt = 0; nt < 4; ++nt)
        acc[mt][nt] = (f32x4){0.f, 0.f, 0.f, 0.f};

    #pragma unroll 1
    for (int kc = 0; kc < KCH; ++kc) {
      const char* qt = Qtiles + (size_t)kc * 16384;
      const char* st = Stiles + ((size_t)nc * KCH + kc) * 16384;

      // kk = 0: 8 direct loads -> 16 MFMA
      {
        short8 a[4], bf[4];
        #pragma unroll
        for (int mt = 0; mt < 4; ++mt)
          a[mt] = *reinterpret_cast<const short8*>(qt + aoff0 + mt * 2048u);
        #pragma unroll
        for (int nt = 0; nt < 4; ++nt)
          bf[nt] = *reinterpret_cast<const short8*>(st + boff0 + nt * 2048u);
        #pragma unroll
        for (int mt = 0; mt < 4; ++mt)
          #pragma unroll
          for (int nt = 0; nt < 4; ++nt)
            acc[mt][nt] = __builtin_amdgcn_mfma_f32_16x16x32_bf16(
                __builtin_bit_cast(bf16x8, a[mt]),
                __builtin_bit_cast(bf16x8, bf[nt]), acc[mt][nt], 0, 0, 0);
      }
      // kk = 1
      {
        short8 a[4], bf[4];
        #pragma unroll
        for (int mt = 0; mt < 4; ++mt)
          a[mt] = *reinterpret_cast<const short8*>(qt + aoff1 + mt * 2048u);
        #pragma unroll
        for (int nt = 0; nt < 4; ++nt)
          bf[nt] = *reinterpret_cast<const short8*>(st + boff1 + nt * 2048u);
        #pragma unroll
        for (int mt = 0; mt < 4; ++mt)
          #pragma unroll
          for (int nt = 0; nt < 4; ++nt)
            acc[mt][nt] = __builtin_amdgcn_mfma_f32_16x16x32_bf16(
                __builtin_bit_cast(bf16x8, a[mt]),
                __builtin_bit_cast(bf16x8, bf[nt]), acc[mt][nt], 0, 0, 0);
      }
    }

    // fold this 128-col chunk into register top-3 (mask pad cols >= 605)
    #pragma unroll
    for (int nt = 0; nt < 4; ++nt) {
      int col = nc * 128 + ncol0 + nt * 16 + l15;
      bool valid = col < SSZ;
      #pragma unroll
      for (int mt = 0; mt < 4; ++mt)
        #pragma unroll
        for (int r = 0; r < 4; ++r) {
          float v = valid ? acc[mt][nt][r] : -3.0e38f;
          ins3(t3a[mt][r], t3b[mt][r], t3c[mt][r], v);
        }
    }
  }

  // butterfly-merge top-3 across the 16 l15 lanes (same rows, different cols)
  #pragma unroll
  for (int m = 1; m < 16; m <<= 1) {
    #pragma unroll
    for (int mt = 0; mt < 4; ++mt)
      #pragma unroll
      for (int r = 0; r < 4; ++r) {
        float o0 = __shfl_xor(t3a[mt][r], m);
        float o1 = __shfl_xor(t3b[mt][r], m);
        float o2 = __shfl_xor(t3c[mt][r], m);
        ins3(t3a[mt][r], t3b[mt][r], t3c[mt][r], o0);
        ins3(t3a[mt][r], t3b[mt][r], t3c[mt][r], o1);
        ins3(t3a[mt][r], t3b[mt][r], t3c[mt][r], o2);
      }
  }

  // cross-half merge via LDS scratch: waves 1,3 publish; 0,2 merge; republish
  __syncthreads();
  if ((wv & 1) == 1 && l15 == 0) {
    #pragma unroll
    for (int mt = 0; mt < 4; ++mt)
      #pragma unroll
      for (int r = 0; r < 4; ++r) {
        int row = mrow0 + mt * 16 + quad * 4 + r;
        tb[row * 3 + 0] = t3a[mt][r];
        tb[row * 3 + 1] = t3b[mt][r];
        tb[row * 3 + 2] = t3c[mt][r];
      }
  }
  __syncthreads();
  if ((wv & 1) == 0 && l15 == 0) {
    #pragma unroll
    for (int mt = 0; mt < 4; ++mt)
      #pragma unroll
      for (int r = 0; r < 4; ++r) {
        int row = mrow0 + mt * 16 + quad * 4 + r;
        ins3(t3a[mt][r], t3b[mt][r], t3c[mt][r], tb[row * 3 + 0]);
        ins3(t3a[mt][r], t3b[mt][r], t3c[mt][r], tb[row * 3 + 1]);
        ins3(t3a[mt][r], t3b[mt][r], t3c[mt][r], tb[row * 3 + 2]);
      }
  }
  __syncthreads();
  if ((wv & 1) == 0 && l15 == 0) {
    #pragma unroll
    for (int mt = 0; mt < 4; ++mt)
      #pragma unroll
      for (int r = 0; r < 4; ++r) {
        int row = mrow0 + mt * 16 + quad * 4 + r;
        tb[row * 3 + 0] = t3a[mt][r];
        tb[row * 3 + 1] = t3b[mt][r];
        tb[row * 3 + 2] = t3c[mt][r];
      }
  }
  __syncthreads();

  // mean over valid rows (<121) and k
  float s = 0.f;
  for (int i = tid; i < PN * TOPK; i += 256) s += tb[i];
  #pragma unroll
  for (int off = 32; off > 0; off >>= 1) s += __shfl_down(s, off);
  if (lane == 0) red[wv] = s;
  __syncthreads();
  if (tid == 0)
    out[bid] = (red[0] + red[1] + red[2] + red[3]) * (1.0f / (PN * TOPK));
}

// ---------------- fallback (direct from fp32, only if ws too small) ---------
__global__ __launch_bounds__(256) void lpc_fallback(
    const float* __restrict__ qf, const float* __restrict__ sf,
    float* __restrict__ out)
{
  __shared__ short Qst[128][72];
  __shared__ short Sst[64][72];
  __shared__ float Cs[128][67];
  __shared__ float top3[128][TOPK];
  __shared__ float red[4];

  const int bid = blockIdx.x;
  const int w   = bid % WAY;
  const int qi  = (bid / WAY) % NQ;
  const int b   = bid / (WAY * NQ);
  const float* Qb = qf + ((size_t)(b * NQ + qi)) * PN * DIM;
  const float* Sb = sf + ((size_t)(b * WAY + w)) * SSZ * DIM;
  const int tid  = threadIdx.x;
  const int lane = tid & 63;
  const int wv   = tid >> 6;
  const int l15  = lane & 15;
  const int quad = lane >> 4;

  if (tid < 128) { top3[tid][0] = -3.0e38f; top3[tid][1] = -3.0e38f; top3[tid][2] = -3.0e38f; }
  f32x4 acc[2][4];
  for (int nc = 0; nc < 10; ++nc) {
    const int sbase = nc * 64;
    int vn = SSZ - sbase; if (vn > 64) vn = 64;
    #pragma unroll
    for (int mt = 0; mt < 2; ++mt)
      #pragma unroll
      for (int nt = 0; nt < 4; ++nt) acc[mt][nt] = (f32x4){0.f,0.f,0.f,0.f};
    for (int kc = 0; kc < KCH; ++kc) {
      const int kbase = kc * 64;
      __syncthreads();
      #pragma unroll
      for (int i = 0; i < 8; ++i) {
        int lin = i * 256 + tid; int row = lin >> 4; int c4 = lin & 15;
        float4 v = make_float4(0.f,0.f,0.f,0.f);
        if (row < PN) v = *reinterpret_cast<const float4*>(Qb + (size_t)row * DIM + kbase + c4 * 4);
        ushort4 h; h.x=f2bf(v.x); h.y=f2bf(v.y); h.z=f2bf(v.z); h.w=f2bf(v.w);
        *reinterpret_cast<ushort4*>(&Qst[row][c4*4]) = h;
      }
      #pragma unroll
      for (int i = 0; i < 4; ++i) {
        int lin = i * 256 + tid; int row = lin >> 4; int c4 = lin & 15;
        int srow = sbase + row;
        float4 v = make_float4(0.f,0.f,0.f,0.f);
        if (srow < SSZ) v = *reinterpret_cast<const float4*>(Sb + (size_t)srow * DIM + kbase + c4 * 4);
        ushort4 h; h.x=f2bf(v.x); h.y=f2bf(v.y); h.z=f2bf(v.z); h.w=f2bf(v.w);
        *reinterpret_cast<ushort4*>(&Sst[row][c4*4]) = h;
      }
      __syncthreads();
      #pragma unroll
      for (int kk = 0; kk < 2; ++kk) {
        bf16x8 a0 = __builtin_bit_cast(bf16x8, *reinterpret_cast<const short8*>(&Qst[wv*32+ 0+l15][kk*32+quad*8]));
        bf16x8 a1 = __builtin_bit_cast(bf16x8, *reinterpret_cast<const short8*>(&Qst[wv*32+16+l15][kk*32+quad*8]));
        #pragma unroll
        for (int nt = 0; nt < 4; ++nt) {
          bf16x8 bb = __builtin_bit_cast(bf16x8, *reinterpret_cast<const short8*>(&Sst[nt*16+l15][kk*32+quad*8]));
          acc[0][nt] = __builtin_amdgcn_mfma_f32_16x16x32_bf16(a0, bb, acc[0][nt], 0,0,0);
          acc[1][nt] = __builtin_amdgcn_mfma_f32_16x16x32_bf16(a1, bb, acc[1][nt], 0,0,0);
        }
      }
    }
    #pragma unroll
    for (int mt = 0; mt < 2; ++mt)
      #pragma unroll
      for (int nt = 0; nt < 4; ++nt)
        #pragma unroll
        for (int r = 0; r < 4; ++r)
          Cs[wv*32+mt*16+quad*4+r][nt*16+l15] = acc[mt][nt][r];
    __syncthreads();
    {
      int row = tid >> 1; int half = tid & 1;
      float a = -3.0e38f, b2 = -3.0e38f, c = -3.0e38f;
      int c0 = half * 32; int cend = c0 + 32; if (cend > vn) cend = vn;
      for (int cc = c0; cc < cend; ++cc) ins3(a, b2, c, Cs[row][cc]);
      float o0 = __shfl_xor(a,1), o1 = __shfl_xor(b2,1), o2 = __shfl_xor(c,1);
      ins3(a,b2,c,o0); ins3(a,b2,c,o1); ins3(a,b2,c,o2);
      if (half == 0) {
        float r0=top3[row][0], r1=top3[row][1], r2=top3[row][2];
        ins3(r0,r1,r2,a); ins3(r0,r1,r2,b2); ins3(r0,r1,r2,c);
        top3[row][0]=r0; top3[row][1]=r1; top3[row][2]=r2;
      }
    }
    __syncthreads();
  }
  float s = 0.f;
  for (int i = tid; i < PN * TOPK; i += 256) s += top3[i/TOPK][i%TOPK];
  #pragma unroll
  for (int off = 32; off > 0; off >>= 1) s += __shfl_down(s, off);
  if (lane == 0) red[wv] = s;
  __syncthreads();
  if (tid == 0) out[bid] = (red[0]+red[1]+red[2]+red[3]) * (1.0f/(PN*TOPK));
}

// ---------------- launch ----------------
extern "C" void kernel_launch(void* const* d_in, const int* in_sizes, int n_in,
                              void* d_out, int out_size, void* d_ws, size_t ws_size,
                              hipStream_t stream) {
  const float* qf = (const float*)d_in[0];
  const float* sf = (const float*)d_in[1];
  float* out = (float*)d_out;
  (void)in_sizes; (void)n_in; (void)out_size;

  if (ws_size >= WS_NEED && d_ws != nullptr) {
    uint4* wq  = (uint4*)d_ws;
    uint4* wsp = wq + (size_t)NQTILES * 1024;
    cvt_pack<<<1600, 256, 0, stream>>>(qf, sf, wq, wsp);
    lpc_main<<<BATCH * NQ * WAY, 256, 0, stream>>>((const char*)wq, (const char*)wsp, out);
  } else {
    lpc_fallback<<<BATCH * NQ * WAY, 256, 0, stream>>>(qf, sf, out);
  }
}

// Round 9
// 631.551 us; speedup vs baseline: 1.7323x; 1.3706x over previous
//
#include <hip/hip_runtime.h>
#include <hip/hip_bf16.h>

// Problem constants:
#define BATCH 8
#define NQ    75
#define WAY   5
#define PN    121
#define DIM   640
#define SSZ   605        // shot * patch_num
#define TOPK  3

#define KCH 10           // DIM / 64
#define NCH 5            // 640 / 128

// Workspace: bf16, MFMA-tile-packed, XOR-swizzled (chunk_phys = chunk_log ^ (row&7)).
//   Q: [bq=600][kc=10] tiles of [row=128][chunk=8]x16B  (6000 tiles)
//   S: [bw=40][nc=5][kc=10] tiles                        (2000 tiles)
#define NQTILES 6000
#define NSTILES 2000
#define WS_NEED   ((size_t)(NQTILES + NSTILES) * 16384)   // 131,072,000 B

// FINAL (round 9): revert to the best-measured configuration (627.1us R0 /
// 627.3us R3, verified twice). Nine-round evidence closes every alternative:
//  * staging/L2 delivery wall ~13.9 TB/s (per-XCD ~1.7 TB/s; 16MB/XCD working
//    set thrashes the 4MB L2): DMA 2-barrier 3blk=13.9 (R0), counted 2blk=11.7
//    (R1), 1blk pipelines 8.0/3.9 (R5/R7), register-direct ~14 equiv but
//    latency-bound (R8).
//  * register-file constraint: 64x64-quadrant wave needs ~164 unified regs;
//    cap = 512/(waves/SIMD). Bigger tiles (acc>64) at >=2 blk/CU need cap>=128
//    -> spill catastrophe (R6: 550MB scratch). <2 blk/CU loses more staging BW
//    than tile economics gain (R1/R5/R7).
//  * cvt_pack ~60-90us (near its traffic roofline); bench dur ~= 1.5x profiled
//    kernel sum (fit across R0/R1/R4/R5).
// => min staged bytes 4.8GB / 13.9 TB/s ~= 345us lpc_main; total ~627us is the
// structural ceiling of this decomposition on this chip.

typedef __attribute__((ext_vector_type(8))) short   short8;
typedef __attribute__((ext_vector_type(8))) __bf16  bf16x8;
typedef __attribute__((ext_vector_type(4))) float   f32x4;

__device__ inline unsigned short f2bf(float f) {
  unsigned u = __builtin_bit_cast(unsigned, f);
  return (unsigned short)((u + 0x7fffu + ((u >> 16) & 1u)) >> 16);
}
__device__ inline unsigned pk2(float lo, float hi) {
  return (unsigned)f2bf(lo) | ((unsigned)f2bf(hi) << 16);
}

// branchless insert into sorted-descending triple: 1 max + 2 med3
__device__ inline void ins3(float &a, float &b, float &c, float v) {
  float na  = fmaxf(a, v);
  float nb  = __builtin_amdgcn_fmed3f(v, a, b);
  float nc2 = __builtin_amdgcn_fmed3f(v, b, c);
  a = na; b = nb; c = nc2;
}

// async 16B global->LDS (DMA; LDS dest = wave-uniform base + lane*16)
__device__ inline void async_copy16(const void* g, void* l) {
  __builtin_amdgcn_global_load_lds(
      (const __attribute__((address_space(1))) unsigned int*)g,
      (__attribute__((address_space(3))) unsigned int*)l, 16, 0, 0);
}

// ---------------- pack kernel: fp32 -> swizzled bf16 tiles in ws -------------
// One block per 64-row slab half; contiguous ~160KB input stream; emits all
// 10 kc tiles for its rows. Measured as part of the 627.3us R3 total.
__global__ __launch_bounds__(256) void cvt_pack(const float* __restrict__ qf,
                                                const float* __restrict__ sf,
                                                uint4* __restrict__ wq,
                                                uint4* __restrict__ wsp) {
  const int blk = blockIdx.x;
  const float* src;      // slab base (row 0 of the 128-row tile frame)
  uint4* dstbase;        // first kc tile of this slab
  int nrows;             // valid rows in the 128-row tile frame
  int rowbase;           // 0 or 64
  if (blk < 1200) {
    const int slab = blk >> 1;
    rowbase = (blk & 1) << 6;
    src = qf + (size_t)slab * PN * DIM;
    dstbase = wq + (size_t)slab * KCH * 1024;
    nrows = PN;
  } else {
    const int u  = blk - 1200;
    const int uv = u >> 1;              // bw*5 + nc
    rowbase = (u & 1) << 6;
    const int nc = uv % NCH;
    const int bw = uv / NCH;
    src = sf + ((size_t)bw * SSZ + nc * 128) * DIM;
    dstbase = wsp + (size_t)uv * KCH * 1024;
    nrows = SSZ - nc * 128; if (nrows > 128) nrows = 128;
  }
  // 64 rows x 80 segments (8 floats in, 16B out each) = 5120 segs, 20 iters.
  #pragma unroll 4
  for (int i = 0; i < 20; ++i) {
    const int L    = i * 256 + threadIdx.x;   // 0..5119
    const int rowl = L / 80;                  // magic-mul div
    const int s    = L - rowl * 80;           // 0..79: global 8-float segment
    const int row  = rowbase + rowl;          // tile-local row 0..127
    const int kc   = s >> 3;
    const int c    = s & 7;                   // logical chunk within kc window
    const int p    = c ^ (row & 7);           // physical chunk slot (swizzle)
    uint4 o = make_uint4(0u, 0u, 0u, 0u);
    if (row < nrows) {
      const float* g = src + (size_t)row * DIM + s * 8;
      float4 v0 = reinterpret_cast<const float4*>(g)[0];
      float4 v1 = reinterpret_cast<const float4*>(g)[1];
      o.x = pk2(v0.x, v0.y); o.y = pk2(v0.z, v0.w);
      o.z = pk2(v1.x, v1.y); o.w = pk2(v1.z, v1.w);
    }
    dstbase[(size_t)kc * 1024 + row * 8 + p] = o;
  }
}

// ---------------- main kernel (R0 structure; measured 341-348us) -------------
// One block per (b,q,w), XCD-swizzled so XCD k owns b=k. 4 waves = 64x64
// quadrants; DMA staging (2-barrier, 3 blocks/CU = inter-block TLP hides the
// vmcnt(0) drain); XOR-swizzled LDS reads (0 conflicts); per-row top-3 in
// registers. __launch_bounds__(256,3): reg cap 170 fits the ~164-reg live set.
__global__ __launch_bounds__(256, 3) void lpc_main(
    const char* __restrict__ wq,    // packed Q tiles
    const char* __restrict__ wsp,   // packed S tiles
    float* __restrict__ out)        // [B, NQ, WAY]
{
  __shared__ char Qs[16384];
  __shared__ char Ss[16384];
  __shared__ float red[4];

  const int sbid = blockIdx.x;
  const int bid  = (sbid & 7) * (NQ * WAY) + (sbid >> 3);

  const int w   = bid % WAY;
  const int bq  = bid / WAY;            // b*NQ + q
  const int b   = bid / (WAY * NQ);

  const char* Qtiles = wq  + (size_t)bq * KCH * 16384;
  const char* Stiles = wsp + (size_t)(b * WAY + w) * NCH * KCH * 16384;

  const int tid  = threadIdx.x;
  const int lane = tid & 63;
  const int wv   = tid >> 6;
  const int l15  = lane & 15;
  const int quad = lane >> 4;
  const int mrow0 = (wv >> 1) * 64;     // quadrant row base
  const int ncol0 = (wv & 1) * 64;      // quadrant col base

  // swizzled chunk byte offsets (XOR distributes over the <<4)
  const int sw16 = (l15 & 7) * 16;
  const int cp0  = (quad * 16) ^ sw16;        // kk = 0
  const int cp1  = ((4 + quad) * 16) ^ sw16;  // kk = 1

  const char* qb = Qs + (mrow0 + l15) * 128;
  const char* sb = Ss + (ncol0 + l15) * 128;

  // per-lane running top-3 for 16 owned rows: row = mrow0 + mt*16 + quad*4 + r
  float t3a[4][4], t3b[4][4], t3c[4][4];
  #pragma unroll
  for (int mt = 0; mt < 4; ++mt)
    #pragma unroll
    for (int r = 0; r < 4; ++r) {
      t3a[mt][r] = -3.0e38f; t3b[mt][r] = -3.0e38f; t3c[mt][r] = -3.0e38f;
    }

  for (int nc = 0; nc < NCH; ++nc) {
    f32x4 acc[4][4];
    #pragma unroll
    for (int mt = 0; mt < 4; ++mt)
      #pragma unroll
      for (int nt = 0; nt < 4; ++nt)
        acc[mt][nt] = (f32x4){0.f, 0.f, 0.f, 0.f};

    #pragma unroll 1
    for (int kc = 0; kc < KCH; ++kc) {
      __syncthreads();   // previous iteration's readers done
      {
        const char* qsl = Qtiles + (size_t)kc * 16384;
        const char* ssl = Stiles + ((size_t)nc * KCH + kc) * 16384;
        #pragma unroll
        for (int i = 0; i < 4; ++i) {
          int ch = wv * 4 + i;
          async_copy16(qsl + ch * 1024 + lane * 16, Qs + ch * 1024);
          async_copy16(ssl + ch * 1024 + lane * 16, Ss + ch * 1024);
        }
      }
      __syncthreads();   // drains vmcnt (DMA complete)

      #pragma unroll
      for (int kk = 0; kk < 2; ++kk) {
        const int cp = kk ? cp1 : cp0;
        short8 a[4], bf[4];
        #pragma unroll
        for (int mt = 0; mt < 4; ++mt)
          a[mt] = *reinterpret_cast<const short8*>(qb + mt * 2048 + cp);
        #pragma unroll
        for (int nt = 0; nt < 4; ++nt)
          bf[nt] = *reinterpret_cast<const short8*>(sb + nt * 2048 + cp);
        #pragma unroll
        for (int mt = 0; mt < 4; ++mt)
          #pragma unroll
          for (int nt = 0; nt < 4; ++nt)
            acc[mt][nt] = __builtin_amdgcn_mfma_f32_16x16x32_bf16(
                __builtin_bit_cast(bf16x8, a[mt]),
                __builtin_bit_cast(bf16x8, bf[nt]), acc[mt][nt], 0, 0, 0);
      }
    }

    // fold this 128-col chunk into register top-3 (mask pad cols >= 605)
    #pragma unroll
    for (int nt = 0; nt < 4; ++nt) {
      int col = nc * 128 + ncol0 + nt * 16 + l15;
      bool valid = col < SSZ;
      #pragma unroll
      for (int mt = 0; mt < 4; ++mt)
        #pragma unroll
        for (int r = 0; r < 4; ++r) {
          float v = valid ? acc[mt][nt][r] : -3.0e38f;
          ins3(t3a[mt][r], t3b[mt][r], t3c[mt][r], v);
        }
    }
  }

  // butterfly-merge top-3 across the 16 l15 lanes (same rows, different cols)
  #pragma unroll
  for (int m = 1; m < 16; m <<= 1) {
    #pragma unroll
    for (int mt = 0; mt < 4; ++mt)
      #pragma unroll
      for (int r = 0; r < 4; ++r) {
        float o0 = __shfl_xor(t3a[mt][r], m);
        float o1 = __shfl_xor(t3b[mt][r], m);
        float o2 = __shfl_xor(t3c[mt][r], m);
        ins3(t3a[mt][r], t3b[mt][r], t3c[mt][r], o0);
        ins3(t3a[mt][r], t3b[mt][r], t3c[mt][r], o1);
        ins3(t3a[mt][r], t3b[mt][r], t3c[mt][r], o2);
      }
  }

  // cross-half merge via LDS scratch (reuse Qs): waves 1,3 publish; 0,2 merge
  float* tb = reinterpret_cast<float*>(Qs);   // [128][3]
  __syncthreads();
  if ((wv & 1) == 1 && l15 == 0) {
    #pragma unroll
    for (int mt = 0; mt < 4; ++mt)
      #pragma unroll
      for (int r = 0; r < 4; ++r) {
        int row = mrow0 + mt * 16 + quad * 4 + r;
        tb[row * 3 + 0] = t3a[mt][r];
        tb[row * 3 + 1] = t3b[mt][r];
        tb[row * 3 + 2] = t3c[mt][r];
      }
  }
  __syncthreads();
  if ((wv & 1) == 0 && l15 == 0) {
    #pragma unroll
    for (int mt = 0; mt < 4; ++mt)
      #pragma unroll
      for (int r = 0; r < 4; ++r) {
        int row = mrow0 + mt * 16 + quad * 4 + r;
        ins3(t3a[mt][r], t3b[mt][r], t3c[mt][r], tb[row * 3 + 0]);
        ins3(t3a[mt][r], t3b[mt][r], t3c[mt][r], tb[row * 3 + 1]);
        ins3(t3a[mt][r], t3b[mt][r], t3c[mt][r], tb[row * 3 + 2]);
      }
  }
  __syncthreads();
  if ((wv & 1) == 0 && l15 == 0) {
    #pragma unroll
    for (int mt = 0; mt < 4; ++mt)
      #pragma unroll
      for (int r = 0; r < 4; ++r) {
        int row = mrow0 + mt * 16 + quad * 4 + r;
        tb[row * 3 + 0] = t3a[mt][r];
        tb[row * 3 + 1] = t3b[mt][r];
        tb[row * 3 + 2] = t3c[mt][r];
      }
  }
  __syncthreads();

  // mean over valid rows (<121) and k
  float s = 0.f;
  for (int i = tid; i < PN * TOPK; i += 256) s += tb[i];
  #pragma unroll
  for (int off = 32; off > 0; off >>= 1) s += __shfl_down(s, off);
  if (lane == 0) red[wv] = s;
  __syncthreads();
  if (tid == 0)
    out[bid] = (red[0] + red[1] + red[2] + red[3]) * (1.0f / (PN * TOPK));
}

// ---------------- fallback (direct from fp32, only if ws too small) ---------
__global__ __launch_bounds__(256) void lpc_fallback(
    const float* __restrict__ qf, const float* __restrict__ sf,
    float* __restrict__ out)
{
  __shared__ short Qst[128][72];
  __shared__ short Sst[64][72];
  __shared__ float Cs[128][67];
  __shared__ float top3[128][TOPK];
  __shared__ float red[4];

  const int bid = blockIdx.x;
  const int w   = bid % WAY;
  const int qi  = (bid / WAY) % NQ;
  const int b   = bid / (WAY * NQ);
  const float* Qb = qf + ((size_t)(b * NQ + qi)) * PN * DIM;
  const float* Sb = sf + ((size_t)(b * WAY + w)) * SSZ * DIM;
  const int tid  = threadIdx.x;
  const int lane = tid & 63;
  const int wv   = tid >> 6;
  const int l15  = lane & 15;
  const int quad = lane >> 4;

  if (tid < 128) { top3[tid][0] = -3.0e38f; top3[tid][1] = -3.0e38f; top3[tid][2] = -3.0e38f; }
  f32x4 acc[2][4];
  for (int nc = 0; nc < 10; ++nc) {
    const int sbase = nc * 64;
    int vn = SSZ - sbase; if (vn > 64) vn = 64;
    #pragma unroll
    for (int mt = 0; mt < 2; ++mt)
      #pragma unroll
      for (int nt = 0; nt < 4; ++nt) acc[mt][nt] = (f32x4){0.f,0.f,0.f,0.f};
    for (int kc = 0; kc < KCH; ++kc) {
      const int kbase = kc * 64;
      __syncthreads();
      #pragma unroll
      for (int i = 0; i < 8; ++i) {
        int lin = i * 256 + tid; int row = lin >> 4; int c4 = lin & 15;
        float4 v = make_float4(0.f,0.f,0.f,0.f);
        if (row < PN) v = *reinterpret_cast<const float4*>(Qb + (size_t)row * DIM + kbase + c4 * 4);
        ushort4 h; h.x=f2bf(v.x); h.y=f2bf(v.y); h.z=f2bf(v.z); h.w=f2bf(v.w);
        *reinterpret_cast<ushort4*>(&Qst[row][c4*4]) = h;
      }
      #pragma unroll
      for (int i = 0; i < 4; ++i) {
        int lin = i * 256 + tid; int row = lin >> 4; int c4 = lin & 15;
        int srow = sbase + row;
        float4 v = make_float4(0.f,0.f,0.f,0.f);
        if (srow < SSZ) v = *reinterpret_cast<const float4*>(Sb + (size_t)srow * DIM + kbase + c4 * 4);
        ushort4 h; h.x=f2bf(v.x); h.y=f2bf(v.y); h.z=f2bf(v.z); h.w=f2bf(v.w);
        *reinterpret_cast<ushort4*>(&Sst[row][c4*4]) = h;
      }
      __syncthreads();
      #pragma unroll
      for (int kk = 0; kk < 2; ++kk) {
        bf16x8 a0 = __builtin_bit_cast(bf16x8, *reinterpret_cast<const short8*>(&Qst[wv*32+ 0+l15][kk*32+quad*8]));
        bf16x8 a1 = __builtin_bit_cast(bf16x8, *reinterpret_cast<const short8*>(&Qst[wv*32+16+l15][kk*32+quad*8]));
        #pragma unroll
        for (int nt = 0; nt < 4; ++nt) {
          bf16x8 bb = __builtin_bit_cast(bf16x8, *reinterpret_cast<const short8*>(&Sst[nt*16+l15][kk*32+quad*8]));
          acc[0][nt] = __builtin_amdgcn_mfma_f32_16x16x32_bf16(a0, bb, acc[0][nt], 0,0,0);
          acc[1][nt] = __builtin_amdgcn_mfma_f32_16x16x32_bf16(a1, bb, acc[1][nt], 0,0,0);
        }
      }
    }
    #pragma unroll
    for (int mt = 0; mt < 2; ++mt)
      #pragma unroll
      for (int nt = 0; nt < 4; ++nt)
        #pragma unroll
        for (int r = 0; r < 4; ++r)
          Cs[wv*32+mt*16+quad*4+r][nt*16+l15] = acc[mt][nt][r];
    __syncthreads();
    {
      int row = tid >> 1; int half = tid & 1;
      float a = -3.0e38f, b2 = -3.0e38f, c = -3.0e38f;
      int c0 = half * 32; int cend = c0 + 32; if (cend > vn) cend = vn;
      for (int cc = c0; cc < cend; ++cc) ins3(a, b2, c, Cs[row][cc]);
      float o0 = __shfl_xor(a,1), o1 = __shfl_xor(b2,1), o2 = __shfl_xor(c,1);
      ins3(a,b2,c,o0); ins3(a,b2,c,o1); ins3(a,b2,c,o2);
      if (half == 0) {
        float r0=top3[row][0], r1=top3[row][1], r2=top3[row][2];
        ins3(r0,r1,r2,a); ins3(r0,r1,r2,b2); ins3(r0,r1,r2,c);
        top3[row][0]=r0; top3[row][1]=r1; top3[row][2]=r2;
      }
    }
    __syncthreads();
  }
  float s = 0.f;
  for (int i = tid; i < PN * TOPK; i += 256) s += top3[i/TOPK][i%TOPK];
  #pragma unroll
  for (int off = 32; off > 0; off >>= 1) s += __shfl_down(s, off);
  if (lane == 0) red[wv] = s;
  __syncthreads();
  if (tid == 0) out[bid] = (red[0]+red[1]+red[2]+red[3]) * (1.0f/(PN*TOPK));
}

// ---------------- launch ----------------
extern "C" void kernel_launch(void* const* d_in, const int* in_sizes, int n_in,
                              void* d_out, int out_size, void* d_ws, size_t ws_size,
                              hipStream_t stream) {
  const float* qf = (const float*)d_in[0];
  const float* sf = (const float*)d_in[1];
  float* out = (float*)d_out;
  (void)in_sizes; (void)n_in; (void)out_size;

  if (ws_size >= WS_NEED && d_ws != nullptr) {
    uint4* wq  = (uint4*)d_ws;
    uint4* wsp = wq + (size_t)NQTILES * 1024;
    cvt_pack<<<1600, 256, 0, stream>>>(qf, sf, wq, wsp);
    lpc_main<<<BATCH * NQ * WAY, 256, 0, stream>>>((const char*)wq, (const char*)wsp, out);
  } else {
    lpc_fallback<<<BATCH * NQ * WAY, 256, 0, stream>>>(qf, sf, out);
  }
}